// Round 9
// baseline (233.321 us; speedup 1.0000x reference)
//
#include <hip/hip_runtime.h>

// Trilerp, FUSED row-assembly + SPATIAL SORT: the untested fourth cell of
// the experiment matrix (clean loads AND clean stores).
//
// Evidence matrix: dirty-loads+dirty-stores=81 (r0), clean-loads+dirty-
// stores=80-83 (r5/r7), dirty-loads+clean-stores=82 (r8). Each fix alone is
// null -> two independent ~80us walls; this kernel fixes both:
//   - counting-sort by lvl3 cell; scatter materializes sorted coords AND
//     sorted mesh features -> all per-slot reads contiguous; corner gathers
//     of bucket-adjacent points are L1/L2 hits (r5: FETCH 127->40 MB).
//   - r8's fused structure: block = 4 sorted slots, 56 lanes/point
//     (8 lvl1 + 16 lvl2 + 32 lvl3) branchless gather; full 227-float row
//     assembled in LDS; stored as ONE contiguous 908-B burst per row to
//     out[perm[slot]] (14 full + 2 edge sectors, vs 4 disjoint partial
//     bursts from 4 different blocks previously).
// Output layout: [B,N,227] = [32 | 64 | 128 | 3 mesh].

typedef float floatx4 __attribute__((ext_vector_type(4)));
// Vector store type with relaxed alignment: out rows stride 908 B, base
// only 4B-aligned; global_store_dwordx4 needs only dword alignment.
typedef float f4u __attribute__((ext_vector_type(4), aligned(4)));

#define NBINS 8192   // 2 batches x 16^3 cells
#define G 4          // points per block
#define THREADS 256

__device__ __forceinline__ int point_batch(int p, int N) {
    int b = 0;
    while (p >= N) { p -= N; ++b; }   // B is tiny (2)
    return b;
}

__device__ __forceinline__ int bucket_of(const float* __restrict__ coords,
                                         int p, int N) {
    const float cx = coords[p * 3 + 0];
    const float cy = coords[p * 3 + 1];
    const float cz = coords[p * 3 + 2];
    int bx = (int)(cx * 16.0f); bx = bx < 0 ? 0 : (bx > 15 ? 15 : bx);
    int by = (int)(cy * 16.0f); by = by < 0 ? 0 : (by > 15 ? 15 : by);
    int bz = (int)(cz * 16.0f); bz = bz < 0 ? 0 : (bz > 15 ? 15 : bz);
    return ((point_batch(p, N) * 16 + bx) * 16 + by) * 16 + bz;
}

__global__ __launch_bounds__(256) void hist_kernel(
    const float* __restrict__ coords, unsigned* __restrict__ bins,
    int N, int P)
{
    const int p = blockIdx.x * 256 + (int)threadIdx.x;
    if (p < P) atomicAdd(&bins[bucket_of(coords, p, N)], 1u);
}

// Exclusive scan of 8192 bins; 1024 threads x 8 bins each.
__global__ __launch_bounds__(1024) void scan_kernel(unsigned* __restrict__ bins)
{
    __shared__ unsigned part[1024];
    const int t = threadIdx.x;
    unsigned loc[8];
    unsigned s = 0;
    for (int i = 0; i < 8; ++i) {
        unsigned v = bins[t * 8 + i];
        loc[i] = s;
        s += v;
    }
    part[t] = s;
    __syncthreads();
    for (int off = 1; off < 1024; off <<= 1) {
        unsigned v = (t >= off) ? part[t - off] : 0u;
        __syncthreads();
        part[t] += v;
        __syncthreads();
    }
    const unsigned base = (t == 0) ? 0u : part[t - 1];
    for (int i = 0; i < 8; ++i) bins[t * 8 + i] = base + loc[i];
}

__global__ __launch_bounds__(256) void scatter_kernel(
    const float* __restrict__ coords, const float* __restrict__ meshf,
    unsigned* __restrict__ bins, unsigned* __restrict__ perm,
    float* __restrict__ csort, float* __restrict__ msort,
    int N, int P)
{
    const int p = blockIdx.x * 256 + (int)threadIdx.x;
    if (p < P) {
        const unsigned pos = atomicAdd(&bins[bucket_of(coords, p, N)], 1u);
        perm[pos] = (unsigned)p;
        csort[pos * 3 + 0] = coords[p * 3 + 0];
        csort[pos * 3 + 1] = coords[p * 3 + 1];
        csort[pos * 3 + 2] = coords[p * 3 + 2];
        msort[pos * 3 + 0] = meshf[p * 3 + 0];
        msort[pos * 3 + 1] = meshf[p * 3 + 1];
        msort[pos * 3 + 2] = meshf[p * 3 + 2];
    }
}

// Bijective chunked XCD swizzle (m204): spatially-adjacent (sorted) blocks
// stay on one XCD's L2.
__device__ __forceinline__ int seg_swz(int lo, int S) {
    const int q = S >> 3, r = S & 7;
    const int xcd = lo & 7, j = lo >> 3;
    return (xcd < r ? xcd * (q + 1) : r * (q + 1) + (xcd - r) * q) + j;
}

// SORTED: nonzero => slot-indexed inputs (csort/msort) + perm output rows.
template<int SORTED>
__device__ __forceinline__ void fused_body(
    const float* __restrict__ f1, const float* __restrict__ f2,
    const float* __restrict__ f3,
    const float* __restrict__ cin,     // csort (sorted) or coords (identity)
    const float* __restrict__ min_,    // msort (sorted) or meshf (identity)
    const unsigned* __restrict__ perm,
    float* __restrict__ out, int blk, int N, int P)
{
    __shared__ float rowbuf[G * 227];  // 3632 B
    __shared__ int   rowp[G];          // output row index per point
    const int tid = (int)threadIdx.x;
    const int s0  = blk * G;

    if (tid < G * 56) {
        const int pt   = tid / 56;
        const int role = tid - pt * 56;
        const int slot = s0 + pt;
        if (slot < P) {
            const int p = SORTED ? (int)perm[slot] : slot;
            if (role == 0) rowp[pt] = p;

            // Branchless per-lane level parameters (uniform instruction
            // stream; no wave divergence).
            const int lvl = (role < 8) ? 0 : ((role < 24) ? 1 : 2);
            const int D   = 64 >> lvl;                   // 64, 32, 16
            const int C   = 32 << lvl;                   // 32, 64, 128
            const int c4  = role - ((lvl == 0) ? 0 : ((lvl == 1) ? 8 : 24));
            const int ocb = (lvl == 0) ? 0 : ((lvl == 1) ? 32 : 96);
            const float* fb = (lvl == 0) ? f1 : ((lvl == 1) ? f2 : f3);

            const int b = (p >= N) ? 1 : 0;

            const float cx = cin[slot * 3 + 0];
            const float cy = cin[slot * 3 + 1];
            const float cz = cin[slot * 3 + 2];

            const float scale = (float)D;                    // 0.5^pow * 128
            const float hi    = (float)((double)D - 1.01);   // matches Python

            const float ix = fminf(fmaxf(cx * scale, 0.01f), hi);
            const float iy = fminf(fmaxf(cy * scale, 0.01f), hi);
            const float iz = fminf(fmaxf(cz * scale, 0.01f), hi);

            const float x1f = floorf(ix), x2f = ceilf(ix);
            const float y1f = floorf(iy), y2f = ceilf(iy);
            const float z1f = floorf(iz), z2f = ceilf(iz);
            const int x1 = (int)x1f, x2 = (int)x2f;
            const int y1 = (int)y1f, y2 = (int)y2f;
            const int z1 = (int)z1f, z2 = (int)z2f;

            // Reference convention: wx multiplies the x2 (ceil) sample.
            const float wx = ix - x1f, wx2 = x2f - ix;
            const float wy = iy - y1f, wy2 = y2f - iy;
            const float wz = iz - z1f, wz2 = z2f - iz;

            #define OFF(X, Y, Z) ((((((b) * D + (X)) * D + (Y)) * D + (Z)) * C) + c4 * 4)
            const floatx4 v111 = *(const floatx4*)(fb + OFF(x1, y1, z1));
            const floatx4 v211 = *(const floatx4*)(fb + OFF(x2, y1, z1));
            const floatx4 v121 = *(const floatx4*)(fb + OFF(x1, y2, z1));
            const floatx4 v221 = *(const floatx4*)(fb + OFF(x2, y2, z1));
            const floatx4 v112 = *(const floatx4*)(fb + OFF(x1, y1, z2));
            const floatx4 v212 = *(const floatx4*)(fb + OFF(x2, y1, z2));
            const floatx4 v122 = *(const floatx4*)(fb + OFF(x1, y2, z2));
            const floatx4 v222 = *(const floatx4*)(fb + OFF(x2, y2, z2));
            #undef OFF

            const floatx4 lx1a = v211 * wx + v111 * wx2;
            const floatx4 lx2a = v221 * wx + v121 * wx2;
            const floatx4 ly1v = lx2a * wy + lx1a * wy2;
            const floatx4 lx1b = v212 * wx + v112 * wx2;
            const floatx4 lx2b = v222 * wx + v122 * wx2;
            const floatx4 ly2v = lx2b * wy + lx1b * wy2;
            const floatx4 r    = ly2v * wz + ly1v * wz2;

            float* rb = rowbuf + pt * 227 + ocb + c4 * 4;
            rb[0] = r.x; rb[1] = r.y; rb[2] = r.z; rb[3] = r.w;
        }
    } else if (tid < G * 56 + G * 3) {
        // mesh tail: contiguous read (msort) in the sorted path
        const int i  = tid - G * 56;
        const int pt = i / 3, c = i - pt * 3;
        const int slot = s0 + pt;
        if (slot < P) rowbuf[pt * 227 + 224 + c] = min_[slot * 3 + c];
    }

    __syncthreads();

    // Store: one contiguous 908-B burst per row at out[rowp[pt]].
    // 4 rows x 57 chunks (56 float4 + 1 tail of 3 floats) = 228 threads.
    if (tid < G * 57) {
        const int pt = tid / 57;
        const int j  = tid - pt * 57;
        const int slot = s0 + pt;
        if (slot < P) {
            const int p = SORTED ? rowp[pt] : slot;
            const float* rb = rowbuf + pt * 227;
            float* o = out + (size_t)p * 227;
            if (j < 56) {
                floatx4 v;
                v.x = rb[j * 4 + 0]; v.y = rb[j * 4 + 1];
                v.z = rb[j * 4 + 2]; v.w = rb[j * 4 + 3];
                __builtin_nontemporal_store(v, (f4u*)(o + j * 4));
            } else {
                __builtin_nontemporal_store(rb[224], o + 224);
                __builtin_nontemporal_store(rb[225], o + 225);
                __builtin_nontemporal_store(rb[226], o + 226);
            }
        }
    }
}

__global__ __launch_bounds__(THREADS, 8) void trilerp_sorted_kernel(
    const float* __restrict__ f1, const float* __restrict__ f2,
    const float* __restrict__ f3, const float* __restrict__ csort,
    const float* __restrict__ msort, const unsigned* __restrict__ perm,
    float* __restrict__ out, int N, int P, int nblk)
{
    const int blk = seg_swz((int)blockIdx.x, nblk);
    fused_body<1>(f1, f2, f3, csort, msort, perm, out, blk, N, P);
}

// Fallback (no workspace): identity order, r8 structure.
__global__ __launch_bounds__(THREADS, 8) void trilerp_fused_kernel(
    const float* __restrict__ f1, const float* __restrict__ f2,
    const float* __restrict__ f3, const float* __restrict__ coords,
    const float* __restrict__ meshf, float* __restrict__ out,
    int N, int P)
{
    fused_body<0>(f1, f2, f3, coords, meshf, nullptr, out,
                  (int)blockIdx.x, N, P);
}

extern "C" void kernel_launch(void* const* d_in, const int* in_sizes, int n_in,
                              void* d_out, int out_size, void* d_ws, size_t ws_size,
                              hipStream_t stream) {
    const float* f1     = (const float*)d_in[1];
    const float* f2     = (const float*)d_in[2];
    const float* f3     = (const float*)d_in[3];
    const float* coords = (const float*)d_in[5];
    const float* meshf  = (const float*)d_in[6];
    float* out = (float*)d_out;

    const int B = in_sizes[1] / (64 * 64 * 64 * 32);
    const int N = in_sizes[5] / (B * 3);
    const int P = B * N;

    // ws: bins | perm | csort | msort
    const size_t ws_need = (size_t)NBINS * 4 + (size_t)P * 4
                         + (size_t)P * 12 + (size_t)P * 12;
    unsigned* bins  = (unsigned*)d_ws;
    unsigned* perm  = bins + NBINS;
    float*    csort = (float*)(perm + P);
    float*    msort = csort + (size_t)P * 3;
    const bool do_sort = (d_ws != nullptr) && (ws_size >= ws_need);

    const int nblk = (P + G - 1) / G;

    if (do_sort) {
        hipMemsetAsync(bins, 0, NBINS * 4, stream);
        const int nbp = (P + 255) / 256;
        hist_kernel<<<dim3(nbp), dim3(256), 0, stream>>>(coords, bins, N, P);
        scan_kernel<<<dim3(1), dim3(1024), 0, stream>>>(bins);
        scatter_kernel<<<dim3(nbp), dim3(256), 0, stream>>>(
            coords, meshf, bins, perm, csort, msort, N, P);
        trilerp_sorted_kernel<<<dim3(nblk), dim3(THREADS), 0, stream>>>(
            f1, f2, f3, csort, msort, perm, out, N, P, nblk);
    } else {
        trilerp_fused_kernel<<<dim3(nblk), dim3(THREADS), 0, stream>>>(
            f1, f2, f3, coords, meshf, out, N, P);
    }
}

// Round 10
// 220.550 us; speedup vs baseline: 1.0579x; 1.0579x over previous
//
#include <hip/hip_runtime.h>

// PERSISTENT grid-stride fused trilerp — the last untested axis.
//
// Evidence: the ~81 us dispatch is invariant under instruction scheduling
// (r0/r1/r3), cache locality (r5: FETCH 127->40 MB), load-request count
// (r7: 5x cut), store shape (r8: full-sector chunks), and both-clean
// (r9: FETCH 39 MB + WRITE 95 MB). No measured pipe is near a ceiling.
// Remaining hypothesis: per-block/per-wave FIXED cost (launch, scalar
// prologue with integer-divide role decode, waitcnt drains, barrier,
// dealloc) x 100k short-lived waves. This kernel:
//   - 2048 persistent blocks (8/CU), grid-stride over 4-point chunks;
//   - per-lane role decode (lvl/D/C/c4/ocb/fbase/scale/hi) hoisted OUT
//     of the loop -- computed once per kernel, not once per point;
//   - double-buffered row LDS -> exactly ONE barrier per iteration;
//   - r8's store shape: 4 rows = 3632 B = 227 float4 contiguous
//     full-sector chunk; identity point order (no sort: never bought
//     kernel time, costs ~20 us harness time).
// Output layout: [B,N,227] = [32 | 64 | 128 | 3 mesh].

typedef float floatx4 __attribute__((ext_vector_type(4)));

#define G 4          // points per iteration per block
#define THREADS 256
#define PBLOCKS 2048 // persistent blocks: 8 per CU

__global__ __launch_bounds__(THREADS, 8) void trilerp_persist_kernel(
    const float* __restrict__ f1,      // [B,64,64,64,32]
    const float* __restrict__ f2,      // [B,32,32,32,64]
    const float* __restrict__ f3,      // [B,16,16,16,128]
    const float* __restrict__ coords,  // [B,N,3]
    const float* __restrict__ meshf,   // [B,N,3]
    float* __restrict__ out,           // [B,N,227]
    int N, int P, int nblk)
{
    __shared__ float rowbuf[2][G * 227];   // 2 x 3632 B
    const int tid = (int)threadIdx.x;

    // ---- hoisted per-lane role decode (loop-invariant) ----
    const int  pt        = tid / 56;             // point-in-chunk for gather
    const int  role      = tid - pt * 56;
    const bool is_gather = tid < G * 56;
    const bool is_mesh   = (tid >= G * 56) && (tid < G * 56 + G * 3);
    const int  mi        = tid - G * 56;         // mesh lane index
    const int  mpt       = mi / 3;
    const int  mc        = mi - mpt * 3;

    const int lvl = (role < 8) ? 0 : ((role < 24) ? 1 : 2);
    const int D   = 64 >> lvl;                   // 64, 32, 16
    const int C   = 32 << lvl;                   // 32, 64, 128
    const int c4  = role - ((lvl == 0) ? 0 : ((lvl == 1) ? 8 : 24));
    const int ocb = (lvl == 0) ? 0 : ((lvl == 1) ? 32 : 96);
    const float* fb = (lvl == 0) ? f1 : ((lvl == 1) ? f2 : f3);
    const float scale = (float)D;                    // 0.5^pow * 128 == D
    const float hi    = (float)((double)D - 1.01);   // matches Python

    int par = 0;
    for (int blk = (int)blockIdx.x; blk < nblk; blk += PBLOCKS, par ^= 1) {
        const int p0 = blk * G;
        float* rbw = rowbuf[par];

        if (is_gather) {
            const int p = p0 + pt;
            if (p < P) {
                const int b = (p >= N) ? 1 : 0;

                const float cx = coords[p * 3 + 0];
                const float cy = coords[p * 3 + 1];
                const float cz = coords[p * 3 + 2];

                const float ix = fminf(fmaxf(cx * scale, 0.01f), hi);
                const float iy = fminf(fmaxf(cy * scale, 0.01f), hi);
                const float iz = fminf(fmaxf(cz * scale, 0.01f), hi);

                const float x1f = floorf(ix), x2f = ceilf(ix);
                const float y1f = floorf(iy), y2f = ceilf(iy);
                const float z1f = floorf(iz), z2f = ceilf(iz);
                const int x1 = (int)x1f, x2 = (int)x2f;
                const int y1 = (int)y1f, y2 = (int)y2f;
                const int z1 = (int)z1f, z2 = (int)z2f;

                // Reference convention: wx multiplies the x2 (ceil) sample.
                const float wx = ix - x1f, wx2 = x2f - ix;
                const float wy = iy - y1f, wy2 = y2f - iy;
                const float wz = iz - z1f, wz2 = z2f - iz;

                #define OFF(X, Y, Z) ((((((b) * D + (X)) * D + (Y)) * D + (Z)) * C) + c4 * 4)
                const floatx4 v111 = *(const floatx4*)(fb + OFF(x1, y1, z1));
                const floatx4 v211 = *(const floatx4*)(fb + OFF(x2, y1, z1));
                const floatx4 v121 = *(const floatx4*)(fb + OFF(x1, y2, z1));
                const floatx4 v221 = *(const floatx4*)(fb + OFF(x2, y2, z1));
                const floatx4 v112 = *(const floatx4*)(fb + OFF(x1, y1, z2));
                const floatx4 v212 = *(const floatx4*)(fb + OFF(x2, y1, z2));
                const floatx4 v122 = *(const floatx4*)(fb + OFF(x1, y2, z2));
                const floatx4 v222 = *(const floatx4*)(fb + OFF(x2, y2, z2));
                #undef OFF

                const floatx4 lx1a = v211 * wx + v111 * wx2;
                const floatx4 lx2a = v221 * wx + v121 * wx2;
                const floatx4 ly1v = lx2a * wy + lx1a * wy2;
                const floatx4 lx1b = v212 * wx + v112 * wx2;
                const floatx4 lx2b = v222 * wx + v122 * wx2;
                const floatx4 ly2v = lx2b * wy + lx1b * wy2;
                const floatx4 r    = ly2v * wz + ly1v * wz2;

                float* rb = rbw + pt * 227 + ocb + c4 * 4;
                rb[0] = r.x; rb[1] = r.y; rb[2] = r.z; rb[3] = r.w;
            }
        } else if (is_mesh) {
            const int p = p0 + mpt;
            if (p < P) rbw[mpt * 227 + 224 + mc] = meshf[p * 3 + mc];
        }

        __syncthreads();

        // Store the chunk. Next iteration writes the OTHER buffer, and
        // every thread's reads here precede the next iteration's barrier,
        // so one barrier per iteration suffices.
        const int nrow = min(G, P - p0);
        if (nrow == G) {
            // 4 rows x 227 floats = 227 float4; chunk base 16B-aligned
            // (p0 % 4 == 0 -> byte offset p0*908 = 3632*k). Full sectors;
            // edges completed by adjacent chunks in L2.
            if (tid < 227) {
                const floatx4 v = *(const floatx4*)(rbw + tid * 4);
                __builtin_nontemporal_store(
                    v, (floatx4*)(out + (size_t)p0 * 227) + tid);
            }
        } else if (nrow > 0) {
            for (int i = tid; i < nrow * 227; i += THREADS)
                out[(size_t)p0 * 227 + i] = rbw[i];
        }
    }
}

extern "C" void kernel_launch(void* const* d_in, const int* in_sizes, int n_in,
                              void* d_out, int out_size, void* d_ws, size_t ws_size,
                              hipStream_t stream) {
    const float* f1     = (const float*)d_in[1];
    const float* f2     = (const float*)d_in[2];
    const float* f3     = (const float*)d_in[3];
    const float* coords = (const float*)d_in[5];
    const float* meshf  = (const float*)d_in[6];
    float* out = (float*)d_out;

    const int B = in_sizes[1] / (64 * 64 * 64 * 32);
    const int N = in_sizes[5] / (B * 3);
    const int P = B * N;

    const int nblk = (P + G - 1) / G;
    const int grid = (nblk < PBLOCKS) ? nblk : PBLOCKS;

    trilerp_persist_kernel<<<dim3(grid), dim3(THREADS), 0, stream>>>(
        f1, f2, f3, coords, meshf, out, N, P, nblk);
}